// Round 15
// baseline (355.645 us; speedup 1.0000x reference)
//
#include <hip/hip_runtime.h>
#include <hip/hip_bf16.h>

#define EPS_LN 1e-5f
#define NB    256             // edge chunks for hist/scatter
#define SEGCAP 16384          // srcList segment capacity per bucket (64KB LDS)

typedef int ivec4 __attribute__((ext_vector_type(4)));
typedef short bf16x8v __attribute__((ext_vector_type(8)));
typedef float f32x4v __attribute__((ext_vector_type(4)));
typedef unsigned short u16x8 __attribute__((ext_vector_type(8)));

// ===========================================================================
// R35: gemm latency/store fixes on R34 (354us).
//  - gemm_mfma: ALL A-loads (AH/AL[4]) issued BEFORE the staging barrier ->
//    global latency hides under the 64KB W stage instead of serializing
//    after it in the K-loop.
//  - gemm_mfma epilogue: scaled bf16 results bounce through the dead Bs
//    buffer as a [128][136]-ushort tile (row stride 272B = 4-bank rotation,
//    conflict-light), then ONE 16B store per thread per pass. Was 32 scalar
//    2B stores/thread (6.4M store instrs per gemm).
//  - aggs/CSR unchanged (aggs pinned at the ~3.3TB/s random-gather path).
// ===========================================================================

__global__ __launch_bounds__(256) void bucket_hist(const int* __restrict__ col,
                                                   int* __restrict__ chunkBH,
                                                   int E, int per, int nbuck) {
    __shared__ int hist[256];
    int t = threadIdx.x;
    hist[t] = 0;
    __syncthreads();
    int s0 = blockIdx.x * per;
    int s1 = s0 + per; if (s1 > E) s1 = E;
    if (s0 < s1) {
        int q0 = s0 >> 2, q1 = s1 >> 2;
        for (int i = q0 + t; i < q1; i += 256) {
            ivec4 c = __builtin_nontemporal_load((const ivec4*)col + i);
            atomicAdd(&hist[c.x >> 8], 1);
            atomicAdd(&hist[c.y >> 8], 1);
            atomicAdd(&hist[c.z >> 8], 1);
            atomicAdd(&hist[c.w >> 8], 1);
        }
        for (int i = (q1 << 2) + t; i < s1; i += 256)
            atomicAdd(&hist[col[i] >> 8], 1);
    }
    __syncthreads();
    if (t < nbuck) chunkBH[blockIdx.x * 256 + t] = hist[t];   // [k][b], coalesced
}

__global__ __launch_bounds__(256) void bucket_scan(int* __restrict__ chunkBH,
                                                   int* __restrict__ bucketStart,
                                                   int* __restrict__ rowPtr,
                                                   int E, int n, int nbuck, int nb) {
    __shared__ int tot[256];
    int t = threadIdx.x;
    int run = 0;
    if (t < nbuck) {
        for (int k0 = 0; k0 < nb; k0 += 16) {
            int v[16];
#pragma unroll
            for (int j = 0; j < 16; j++)
                v[j] = (k0 + j < nb) ? chunkBH[(k0 + j) * 256 + t] : 0;
#pragma unroll
            for (int j = 0; j < 16; j++) {
                int tv = v[j];
                if (k0 + j < nb) chunkBH[(k0 + j) * 256 + t] = run;
                run += tv;
            }
        }
    }
    tot[t] = run;
    __syncthreads();
    for (int d = 1; d < 256; d <<= 1) {
        int add = (t >= d) ? tot[t - d] : 0;
        __syncthreads();
        tot[t] += add;
        __syncthreads();
    }
    if (t < nbuck) bucketStart[t] = tot[t] - run;
    if (t == 0) { bucketStart[nbuck] = E; rowPtr[n] = E; }
}

__global__ __launch_bounds__(256) void scatter_pairs(const int* __restrict__ row,
                                                     const int* __restrict__ col,
                                                     const int* __restrict__ chunkBH,
                                                     const int* __restrict__ bucketStart,
                                                     unsigned int* __restrict__ tmp,
                                                     int E, int per, int nbuck) {
    __shared__ int curs[256];
    int t = threadIdx.x;
    int k = blockIdx.x;
    curs[t] = (t < nbuck) ? (chunkBH[k * 256 + t] + bucketStart[t]) : 0;
    __syncthreads();
    int s0 = k * per;
    int s1 = s0 + per; if (s1 > E) s1 = E;
    if (s0 >= s1) return;
    int q0 = s0 >> 2, q1 = s1 >> 2;
    for (int i = q0 + t; i < q1; i += 256) {
        ivec4 c4 = __builtin_nontemporal_load((const ivec4*)col + i);
        ivec4 r4 = __builtin_nontemporal_load((const ivec4*)row + i);
        int p0 = atomicAdd(&curs[c4.x >> 8], 1);
        tmp[p0] = ((unsigned)(c4.x & 255) << 24) | (unsigned)r4.x;
        int p1 = atomicAdd(&curs[c4.y >> 8], 1);
        tmp[p1] = ((unsigned)(c4.y & 255) << 24) | (unsigned)r4.y;
        int p2 = atomicAdd(&curs[c4.z >> 8], 1);
        tmp[p2] = ((unsigned)(c4.z & 255) << 24) | (unsigned)r4.z;
        int p3 = atomicAdd(&curs[c4.w >> 8], 1);
        tmp[p3] = ((unsigned)(c4.w & 255) << 24) | (unsigned)r4.w;
    }
    for (int i = (q1 << 2) + t; i < s1; i += 256) {
        int c = col[i], r = row[i];
        int p = atomicAdd(&curs[c >> 8], 1);
        tmp[p] = ((unsigned)(c & 255) << 24) | (unsigned)r;
    }
}

__global__ __launch_bounds__(256) void bucket_fill(const unsigned int* __restrict__ tmp,
                                                   const int* __restrict__ bucketStart,
                                                   int* __restrict__ rowPtr,
                                                   float* __restrict__ dinv,
                                                   int* __restrict__ srcList,
                                                   int n) {
    __shared__ int cnt[256];
    __shared__ int cur[256];
    __shared__ int seg[SEGCAP];
    int b = blockIdx.x, t = threadIdx.x;
    int node0 = b << 8;
    int s0 = bucketStart[b], s1 = bucketStart[b + 1];
    int len = s1 - s0;
    cnt[t] = 0;
    __syncthreads();
    for (int i = s0 + t; i < s1; i += 256) {
        atomicAdd(&cnt[tmp[i] >> 24], 1);
    }
    __syncthreads();
    int v = cnt[t];
    cur[t] = v;
    __syncthreads();
    for (int d = 1; d < 256; d <<= 1) {
        int add = (t >= d) ? cur[t - d] : 0;
        __syncthreads();
        cur[t] += add;
        __syncthreads();
    }
    int excl = cur[t] - v;
    int node = node0 + t;
    if (node < n) {
        rowPtr[node] = s0 + excl;
        dinv[node] = rsqrtf((float)v + 1.0f);   // +1 self-loop
    }
    cur[t] = excl;
    __syncthreads();
    if (len <= SEGCAP) {
        for (int i = s0 + t; i < s1; i += 256) {
            unsigned int p = tmp[i];
            int pos = atomicAdd(&cur[p >> 24], 1);
            seg[pos] = (int)(p & 0xffffffu);
        }
        __syncthreads();
        for (int i = t; i < len; i += 256)
            srcList[s0 + i] = seg[i];
    } else {                                    // overflow fallback (never for this graph)
        for (int i = s0 + t; i < s1; i += 256) {
            unsigned int p = tmp[i];
            int pos = atomicAdd(&cur[p >> 24], 1);
            srcList[s0 + pos] = (int)(p & 0xffffffu);
        }
    }
}

// ---------------------------------------------------------------------------
// pack_w_all + head_collapse fused. Blocks 0..191: pack W1/W2/W3 into MFMA
// B-fragment bf16 hi/lo planes. Block 192: Weff = Wp1@Wp2, beff = bp1@Wp2+bp2.
// ---------------------------------------------------------------------------
__global__ __launch_bounds__(256) void pack_w_all(const float* __restrict__ W1,
                                                  const float* __restrict__ W2,
                                                  const float* __restrict__ W3,
                                                  unsigned short* __restrict__ Wq,
                                                  const float* __restrict__ Wp1,
                                                  const float* __restrict__ bp1,
                                                  const float* __restrict__ Wp2,
                                                  const float* __restrict__ bp2,
                                                  float* __restrict__ Weff,
                                                  float* __restrict__ beff) {
    if (blockIdx.x == 192) {                     // head collapse
        __shared__ float w2[384];
        int t = threadIdx.x;
        for (int idx = t; idx < 384; idx += 256) w2[idx] = Wp2[idx];
        __syncthreads();
        if (t < 128) {
            float p0 = 0.f, p1 = 0.f, p2 = 0.f;
            const float* wr = Wp1 + (size_t)t * 128;
            for (int k = 0; k < 128; k++) {
                float v = wr[k];
                p0 += v * w2[k * 3 + 0];
                p1 += v * w2[k * 3 + 1];
                p2 += v * w2[k * 3 + 2];
            }
            Weff[t * 3 + 0] = p0; Weff[t * 3 + 1] = p1; Weff[t * 3 + 2] = p2;
            if (t == 0) {
                float q0 = bp2[0], q1 = bp2[1], q2 = bp2[2];
                for (int k = 0; k < 128; k++) {
                    float v = bp1[k];
                    q0 += v * w2[k * 3 + 0];
                    q1 += v * w2[k * 3 + 1];
                    q2 += v * w2[k * 3 + 2];
                }
                beff[0] = q0; beff[1] = q1; beff[2] = q2;
            }
        }
        return;
    }
    int w = blockIdx.x >> 6;
    const float* W = (w == 0) ? W1 : (w == 1) ? W2 : W3;
    unsigned short* Wp = Wq + (size_t)w * 32768;
    int s = (blockIdx.x & 63) * 256 + threadIdx.x;   // 0..16383
    int i = s & 7;
    int lane = (s >> 3) & 63;
    int jt = (s >> 9) & 7;
    int kb = s >> 12;
    int k = kb * 32 + ((lane >> 4) & 3) * 8 + i;
    int nn = jt * 16 + (lane & 15);
    float v = W[k * 128 + nn];
    __hip_bfloat16 hi = __float2bfloat16(v);
    float hf = __bfloat162float(hi);
    __hip_bfloat16 lo = __float2bfloat16(v - hf);
    Wp[s]         = *(unsigned short*)&hi;
    Wp[16384 + s] = *(unsigned short*)&lo;
}

// ---------------------------------------------------------------------------
// MFMA gemm: 128-row tile, 512 threads (8 waves x 16 rows). Full packed W
// (64KB) staged once; A-loads hoisted above the barrier; K-loop barrier-free;
// LDS-transposed vectorized epilogue.
// ---------------------------------------------------------------------------
__device__ __forceinline__ void split8(const float* __restrict__ p,
                                       bf16x8v& ah, bf16x8v& al) {
#pragma unroll
    for (int i = 0; i < 8; i++) {
        float v = p[i];
        __hip_bfloat16 hb = __float2bfloat16(v);
        float hf = __bfloat162float(hb);
        __hip_bfloat16 lb = __float2bfloat16(v - hf);
        ah[i] = *(short*)&hb;
        al[i] = *(short*)&lb;
    }
}

template<int ASRC>   // 0: f32 A (split in-register), 1: hi/lo bf16 planes
__global__ __launch_bounds__(512) void gemm_mfma(const float* __restrict__ Af32,
                                                 const unsigned short* __restrict__ Ahi,
                                                 const unsigned short* __restrict__ Alo,
                                                 const unsigned short* __restrict__ Wp,
                                                 const float* __restrict__ dinv,
                                                 unsigned short* __restrict__ hbOut,
                                                 int n) {
    __shared__ unsigned short Bs[32768];  // full W hi||lo; reused as C tile

    const int tx = threadIdx.x;
    const int wv = tx >> 6;               // 0..7
    const int l  = tx & 63;
    const int base = blockIdx.x * 128;
    const int m0 = base + wv * 16;
    int arow = m0 + (l & 15);
    if (arow >= n) arow = 0;            // clamped rows only affect unstored outputs
    const int kofs = (l >> 4) * 8;

    // --- A loads first: fill during the staging + barrier ---
    bf16x8v AH[4], AL[4];
    if (ASRC == 0) {
        float af[32];
#pragma unroll
        for (int kb = 0; kb < 4; kb++) {
            *(float4*)&af[kb * 8]     = *(const float4*)(Af32 + (size_t)arow * 128 + kb * 32 + kofs);
            *(float4*)&af[kb * 8 + 4] = *(const float4*)(Af32 + (size_t)arow * 128 + kb * 32 + kofs + 4);
        }
#pragma unroll
        for (int kb = 0; kb < 4; kb++) split8(&af[kb * 8], AH[kb], AL[kb]);
    } else {
#pragma unroll
        for (int kb = 0; kb < 4; kb++) {
            AH[kb] = *(const bf16x8v*)(Ahi + (size_t)arow * 128 + kb * 32 + kofs);
            AL[kb] = *(const bf16x8v*)(Alo + (size_t)arow * 128 + kb * 32 + kofs);
        }
    }

    // stage full W: 512 threads x 8 chunks x 16B = 64KB, coalesced
#pragma unroll
    for (int i = 0; i < 8; i++)
        *(u16x8*)&Bs[tx * 8 + i * 4096] = *(const u16x8*)(Wp + tx * 8 + i * 4096);

    f32x4v acc[8];
#pragma unroll
    for (int jt = 0; jt < 8; jt++) acc[jt] = (f32x4v){0.f, 0.f, 0.f, 0.f};

    __syncthreads();

#pragma unroll
    for (int kb = 0; kb < 4; kb++) {
#pragma unroll
        for (int jt = 0; jt < 8; jt++) {
            bf16x8v bh = *(const bf16x8v*)&Bs[kb * 4096 + jt * 512 + l * 8];
            bf16x8v bl = *(const bf16x8v*)&Bs[16384 + kb * 4096 + jt * 512 + l * 8];
            acc[jt] = __builtin_amdgcn_mfma_f32_16x16x32_bf16(AH[kb], bh, acc[jt], 0, 0, 0);
            acc[jt] = __builtin_amdgcn_mfma_f32_16x16x32_bf16(AH[kb], bl, acc[jt], 0, 0, 0);
            acc[jt] = __builtin_amdgcn_mfma_f32_16x16x32_bf16(AL[kb], bh, acc[jt], 0, 0, 0);
        }
    }

    __syncthreads();                      // all Bs reads done; reuse as C tile
    unsigned short* Cs = Bs;              // [128][136] ushorts (34KB)
    {
        const int lr0 = wv * 16 + (l >> 4) * 4;   // local row base
        const int colb = l & 15;
#pragma unroll
        for (int r = 0; r < 4; r++) {
            int lrow = lr0 + r;
            int grow = base + lrow;
            float dv = (grow < n) ? dinv[grow] : 0.f;
#pragma unroll
            for (int jt = 0; jt < 8; jt++) {
                __hip_bfloat16 t = __float2bfloat16(acc[jt][r] * dv);
                Cs[lrow * 136 + jt * 16 + colb] = *(unsigned short*)&t;
            }
        }
    }
    __syncthreads();
#pragma unroll
    for (int p = 0; p < 4; p++) {
        int idx = p * 4096 + tx * 8;      // ushort index in 128x128
        int orow = idx >> 7;
        int ocol = idx & 127;
        int grow = base + orow;
        if (grow < n)
            *(u16x8*)(hbOut + (size_t)grow * 128 + ocol) =
                *(const u16x8*)&Cs[orow * 136 + ocol];
    }
}

#define BF_LO(u) __uint_as_float((u) << 16)
#define BF_HI(u) __uint_as_float((u) & 0xffff0000u)

#define ACC8(u)  do { \
    a[0] += BF_LO((u).x); a[1] += BF_HI((u).x); \
    a[2] += BF_LO((u).y); a[3] += BF_HI((u).y); \
    a[4] += BF_LO((u).z); a[5] += BF_HI((u).z); \
    a[6] += BF_LO((u).w); a[7] += BF_HI((u).w); } while (0)

// ---------------------------------------------------------------------------
// agg_post (LN layers): 8-edge unrolled gather (24 VGPR, 70% occ);
// output = hi/lo bf16 planes.
// ---------------------------------------------------------------------------
__global__ __launch_bounds__(128) void agg_post(const unsigned int* __restrict__ hb,
                                                const int* __restrict__ rowPtr,
                                                const int* __restrict__ srcList,
                                                const float* __restrict__ dinv,
                                                const float* __restrict__ b,
                                                const float* __restrict__ g,
                                                const float* __restrict__ beta,
                                                unsigned short* __restrict__ outHi,
                                                unsigned short* __restrict__ outLo,
                                                int n) {
    int wid = (blockIdx.x * 128 + threadIdx.x) >> 6;
    int lane = threadIdx.x & 63;
    if (wid >= n) return;
    int h = lane & 15;
    int gg = lane >> 4;
    int e0 = rowPtr[wid], e1 = rowPtr[wid + 1];
    float dc = dinv[wid];
    const uint4* hb4 = (const uint4*)hb;

    uint4 us = hb4[(size_t)wid * 16 + h];

    float a[8];
#pragma unroll
    for (int j = 0; j < 8; j++) a[j] = 0.f;

    int idx0 = (e0 + gg < e1) ? srcList[e0 + gg] : -1;
    int idx1 = (e0 + 4 + gg < e1) ? srcList[e0 + 4 + gg] : -1;
    int e = e0;
    for (; e + 8 <= e1; e += 8) {
        int ni0 = (e + 8 + gg < e1) ? srcList[e + 8 + gg] : -1;
        int ni1 = (e + 12 + gg < e1) ? srcList[e + 12 + gg] : -1;
        uint4 u0 = hb4[(size_t)idx0 * 16 + h];
        uint4 u1 = hb4[(size_t)idx1 * 16 + h];
        ACC8(u0); ACC8(u1);
        idx0 = ni0; idx1 = ni1;
    }
    if (idx0 >= 0) { uint4 u = hb4[(size_t)idx0 * 16 + h]; ACC8(u); }
    if (idx1 >= 0) { uint4 u = hb4[(size_t)idx1 * 16 + h]; ACC8(u); }

#pragma unroll
    for (int j = 0; j < 8; j++) {
        a[j] += __shfl_xor(a[j], 16, 64);
        a[j] += __shfl_xor(a[j], 32, 64);
    }
    ACC8(us);   // self-loop, same dc scaling as gather terms

    float4 bv0 = *(const float4*)(b + h * 8);
    float4 bv1 = *(const float4*)(b + h * 8 + 4);
    a[0] = fmaxf(a[0] * dc + bv0.x, 0.f);
    a[1] = fmaxf(a[1] * dc + bv0.y, 0.f);
    a[2] = fmaxf(a[2] * dc + bv0.z, 0.f);
    a[3] = fmaxf(a[3] * dc + bv0.w, 0.f);
    a[4] = fmaxf(a[4] * dc + bv1.x, 0.f);
    a[5] = fmaxf(a[5] * dc + bv1.y, 0.f);
    a[6] = fmaxf(a[6] * dc + bv1.z, 0.f);
    a[7] = fmaxf(a[7] * dc + bv1.w, 0.f);

    float s = ((a[0] + a[1]) + (a[2] + a[3])) + ((a[4] + a[5]) + (a[6] + a[7]));
#pragma unroll
    for (int m = 8; m >= 1; m >>= 1) s += __shfl_xor(s, m, 64);
    float mu = s * (1.f / 128.f);
    float sq = 0.f;
    float d[8];
#pragma unroll
    for (int j = 0; j < 8; j++) { d[j] = a[j] - mu; sq += d[j] * d[j]; }
#pragma unroll
    for (int m = 8; m >= 1; m >>= 1) sq += __shfl_xor(sq, m, 64);
    float rs = rsqrtf(sq * (1.f / 128.f) + EPS_LN);
    float4 gv0 = *(const float4*)(g + h * 8);
    float4 gv1 = *(const float4*)(g + h * 8 + 4);
    float4 bt0 = *(const float4*)(beta + h * 8);
    float4 bt1 = *(const float4*)(beta + h * 8 + 4);
    a[0] = d[0] * rs * gv0.x + bt0.x;
    a[1] = d[1] * rs * gv0.y + bt0.y;
    a[2] = d[2] * rs * gv0.z + bt0.z;
    a[3] = d[3] * rs * gv0.w + bt0.w;
    a[4] = d[4] * rs * gv1.x + bt1.x;
    a[5] = d[5] * rs * gv1.y + bt1.y;
    a[6] = d[6] * rs * gv1.z + bt1.z;
    a[7] = d[7] * rs * gv1.w + bt1.w;

    if (gg == 0) {
        ushort4 h0, h1, l0, l1;
        __hip_bfloat16 bb; float ff;
        bb = __float2bfloat16(a[0]); ff = __bfloat162float(bb); h0.x = *(unsigned short*)&bb;
        bb = __float2bfloat16(a[0] - ff); l0.x = *(unsigned short*)&bb;
        bb = __float2bfloat16(a[1]); ff = __bfloat162float(bb); h0.y = *(unsigned short*)&bb;
        bb = __float2bfloat16(a[1] - ff); l0.y = *(unsigned short*)&bb;
        bb = __float2bfloat16(a[2]); ff = __bfloat162float(bb); h0.z = *(unsigned short*)&bb;
        bb = __float2bfloat16(a[2] - ff); l0.z = *(unsigned short*)&bb;
        bb = __float2bfloat16(a[3]); ff = __bfloat162float(bb); h0.w = *(unsigned short*)&bb;
        bb = __float2bfloat16(a[3] - ff); l0.w = *(unsigned short*)&bb;
        bb = __float2bfloat16(a[4]); ff = __bfloat162float(bb); h1.x = *(unsigned short*)&bb;
        bb = __float2bfloat16(a[4] - ff); l1.x = *(unsigned short*)&bb;
        bb = __float2bfloat16(a[5]); ff = __bfloat162float(bb); h1.y = *(unsigned short*)&bb;
        bb = __float2bfloat16(a[5] - ff); l1.y = *(unsigned short*)&bb;
        bb = __float2bfloat16(a[6]); ff = __bfloat162float(bb); h1.z = *(unsigned short*)&bb;
        bb = __float2bfloat16(a[6] - ff); l1.z = *(unsigned short*)&bb;
        bb = __float2bfloat16(a[7]); ff = __bfloat162float(bb); h1.w = *(unsigned short*)&bb;
        bb = __float2bfloat16(a[7] - ff); l1.w = *(unsigned short*)&bb;
        size_t base = (size_t)wid * 128 + h * 8;
        *(ushort4*)(outHi + base)     = h0;
        *(ushort4*)(outHi + base + 4) = h1;
        *(ushort4*)(outLo + base)     = l0;
        *(ushort4*)(outLo + base + 4) = l1;
    }
}

// ---------------------------------------------------------------------------
// Fused layer-3 agg (relu, no LN) + collapsed head. Head weights loaded into
// registers AFTER the gather loop (low peak VGPR). No LDS.
// ---------------------------------------------------------------------------
__global__ __launch_bounds__(128) void agg_head(
        const unsigned int* __restrict__ hb,
        const int* __restrict__ rowPtr,
        const int* __restrict__ srcList,
        const float* __restrict__ dinv,
        const float* __restrict__ b,
        const float* __restrict__ Weff,
        const float* __restrict__ beff,
        float* __restrict__ out, int n) {
    int tt = threadIdx.x;
    int wid = (blockIdx.x * 128 + tt) >> 6;
    int lane = tt & 63;
    if (wid >= n) return;
    int h = lane & 15;
    int gg = lane >> 4;
    int e0 = rowPtr[wid], e1 = rowPtr[wid + 1];
    float dc = dinv[wid];
    const uint4* hb4 = (const uint4*)hb;
    uint4 us = hb4[(size_t)wid * 16 + h];

    float a[8];
#pragma unroll
    for (int j = 0; j < 8; j++) a[j] = 0.f;

    int idx0 = (e0 + gg < e1) ? srcList[e0 + gg] : -1;
    int idx1 = (e0 + 4 + gg < e1) ? srcList[e0 + 4 + gg] : -1;
    int e = e0;
    for (; e + 8 <= e1; e += 8) {
        int ni0 = (e + 8 + gg < e1) ? srcList[e + 8 + gg] : -1;
        int ni1 = (e + 12 + gg < e1) ? srcList[e + 12 + gg] : -1;
        uint4 u0 = hb4[(size_t)idx0 * 16 + h];
        uint4 u1 = hb4[(size_t)idx1 * 16 + h];
        ACC8(u0); ACC8(u1);
        idx0 = ni0; idx1 = ni1;
    }
    if (idx0 >= 0) { uint4 u = hb4[(size_t)idx0 * 16 + h]; ACC8(u); }
    if (idx1 >= 0) { uint4 u = hb4[(size_t)idx1 * 16 + h]; ACC8(u); }

#pragma unroll
    for (int j = 0; j < 8; j++) {
        a[j] += __shfl_xor(a[j], 16, 64);
        a[j] += __shfl_xor(a[j], 32, 64);
    }
    ACC8(us);

    float4 bv0 = *(const float4*)(b + h * 8);
    float4 bv1 = *(const float4*)(b + h * 8 + 4);
    a[0] = fmaxf(a[0] * dc + bv0.x, 0.f);
    a[1] = fmaxf(a[1] * dc + bv0.y, 0.f);
    a[2] = fmaxf(a[2] * dc + bv0.z, 0.f);
    a[3] = fmaxf(a[3] * dc + bv0.w, 0.f);
    a[4] = fmaxf(a[4] * dc + bv1.x, 0.f);
    a[5] = fmaxf(a[5] * dc + bv1.y, 0.f);
    a[6] = fmaxf(a[6] * dc + bv1.z, 0.f);
    a[7] = fmaxf(a[7] * dc + bv1.w, 0.f);

    // head weights loaded AFTER gather (gather regs dead): 6x float4
    float p0 = 0.f, p1 = 0.f, p2 = 0.f;
    {
        const float4* wp = (const float4*)(Weff + 24 * h);
#pragma unroll
        for (int q = 0; q < 2; q++) {
            float4 w0 = wp[3 * q + 0];
            float4 w1 = wp[3 * q + 1];
            float4 w2 = wp[3 * q + 2];
            const float* aw = &a[4 * q];
            p0 += aw[0] * w0.x + aw[1] * w0.w + aw[2] * w1.z + aw[3] * w2.y;
            p1 += aw[0] * w0.y + aw[1] * w1.x + aw[2] * w1.w + aw[3] * w2.z;
            p2 += aw[0] * w0.z + aw[1] * w1.y + aw[2] * w2.x + aw[3] * w2.w;
        }
    }
#pragma unroll
    for (int m = 8; m >= 1; m >>= 1) {
        p0 += __shfl_xor(p0, m, 64);
        p1 += __shfl_xor(p1, m, 64);
        p2 += __shfl_xor(p2, m, 64);
    }
    if (lane == 0) {
        out[(size_t)wid * 3 + 0] = p0 + beff[0];
        out[(size_t)wid * 3 + 1] = p1 + beff[1];
        out[(size_t)wid * 3 + 2] = p2 + beff[2];
    }
}

// ---------------------------------------------------------------------------
extern "C" void kernel_launch(void* const* d_in, const int* in_sizes, int n_in,
                              void* d_out, int out_size, void* d_ws, size_t ws_size,
                              hipStream_t stream) {
    const float* x   = (const float*)d_in[0];
    const int* ei    = (const int*)d_in[1];
    const float* W1  = (const float*)d_in[2];
    const float* b1  = (const float*)d_in[3];
    const float* W2  = (const float*)d_in[4];
    const float* b2  = (const float*)d_in[5];
    const float* W3  = (const float*)d_in[6];
    const float* b3  = (const float*)d_in[7];
    const float* g1  = (const float*)d_in[8];
    const float* be1 = (const float*)d_in[9];
    const float* g2  = (const float*)d_in[10];
    const float* be2 = (const float*)d_in[11];
    const float* Wp1f = (const float*)d_in[12];
    const float* bp1 = (const float*)d_in[13];
    const float* Wp2f = (const float*)d_in[14];
    const float* bp2 = (const float*)d_in[15];
    float* out = (float*)d_out;

    const int n = in_sizes[0] / 128;   // 50000
    const int E = in_sizes[1] / 2;     // 1600000
    const int* row = ei;
    const int* col = ei + E;

    char* ws = (char*)d_ws;
    size_t nA  = ((size_t)n * 4 + 255) & ~(size_t)255;
    size_t nA1 = ((size_t)(n + 1) * 4 + 255) & ~(size_t)255;
    size_t eA  = ((size_t)E * 4 + 255) & ~(size_t)255;
    size_t hbSz = ((size_t)n * 128 * 2 + 255) & ~(size_t)255;
    int*   rowPtr  = (int*)ws;
    float* dinvp   = (float*)(ws + nA1);
    int*   srcList = (int*)(ws + nA1 + nA);
    unsigned short* hbA = (unsigned short*)(ws + nA1 + nA + eA);
    unsigned short* hbB = hbA + hbSz / 2;
    unsigned short* Phi = hbB + hbSz / 2;
    unsigned short* Plo = Phi + hbSz / 2;
    unsigned short* Wq  = Plo + hbSz / 2;        // 3 x 32768 ushorts
    float* Weff = (float*)(Wq + 3 * 32768);
    float* beff = Weff + 384;
    // CSR scratch aliases Phi (consumed by bucket_fill before agg writes):
    unsigned int* tmp = (unsigned int*)Phi;      // eA bytes (packed pairs)
    int* chunkBH     = (int*)((char*)Phi + eA);
    int* bucketStart = (int*)((char*)Phi + eA + (size_t)NB * 256 * 4);

    const int nbuck = (n + 255) >> 8;                 // 196
    const int per   = (((E + NB - 1) / NB) + 15) & ~15;
    const int tileBlocks = (n + 127) / 128;           // 391
    const int nodeWaveBlocks = (n + 1) / 2;           // 25000

    // CSR build (bucketed counting sort, zero global atomics)
    bucket_hist<<<NB, 256, 0, stream>>>(col, chunkBH, E, per, nbuck);
    bucket_scan<<<1, 256, 0, stream>>>(chunkBH, bucketStart, rowPtr, E, n, nbuck, NB);
    scatter_pairs<<<NB, 256, 0, stream>>>(row, col, chunkBH, bucketStart, tmp, E, per, nbuck);
    bucket_fill<<<nbuck, 256, 0, stream>>>(tmp, bucketStart, rowPtr, dinvp, srcList, n);
    pack_w_all<<<193, 256, 0, stream>>>(W1, W2, W3, Wq, Wp1f, bp1, Wp2f, bp2, Weff, beff);

    // ---- layer 1 (x f32 -> in-register hi/lo split) ----
    gemm_mfma<0><<<tileBlocks, 512, 0, stream>>>(x, nullptr, nullptr, Wq, dinvp, hbA, n);
    agg_post<<<nodeWaveBlocks, 128, 0, stream>>>((const unsigned int*)hbA,
                                                 rowPtr, srcList, dinvp,
                                                 b1, g1, be1, Phi, Plo, n);
    // ---- layer 2 ----
    gemm_mfma<1><<<tileBlocks, 512, 0, stream>>>(nullptr, Phi, Plo, Wq + 32768, dinvp, hbB, n);
    agg_post<<<nodeWaveBlocks, 128, 0, stream>>>((const unsigned int*)hbB,
                                                 rowPtr, srcList, dinvp,
                                                 b2, g2, be2, Phi, Plo, n);
    // ---- layer 3 ----
    gemm_mfma<1><<<tileBlocks, 512, 0, stream>>>(nullptr, Phi, Plo, Wq + 65536, dinvp, hbA, n);
    agg_head<<<nodeWaveBlocks, 128, 0, stream>>>((const unsigned int*)hbA,
                                                 rowPtr, srcList, dinvp,
                                                 b3, Weff, beff, out, n);
}